// Round 3
// baseline (115759.412 us; speedup 1.0000x reference)
//
#include <hip/hip_runtime.h>

#define NTOK 32768
#define DIMD 512
#define NE   8192

// d_out layout (floats): quantize_st | embed_ind | loss | dist
#define Q_OFF    0
#define IND_OFF  16777216
#define LOSS_OFF 16809984
#define DIST_OFF 16809985

// d_ws layout (bytes): packed u64[32768] @0 ; x2 f32[32768] @262144 ; e2 f32[8192] @393216

__global__ __launch_bounds__(256) void init_k(unsigned long long* __restrict__ packed,
                                              float* __restrict__ loss) {
    int i = blockIdx.x * 256 + threadIdx.x;
    if (i < NTOK) packed[i] = ~0ULL;
    if (i == 0) *loss = 0.0f;
}

__global__ __launch_bounds__(256) void rowsq_k(const float* __restrict__ X,
                                               float* __restrict__ x2) {
    int wid = threadIdx.x >> 6, lane = threadIdx.x & 63;
    int row = blockIdx.x * 4 + wid;
    const float* xp = X + (size_t)row * DIMD;
    float s = 0.f;
#pragma unroll
    for (int j = 0; j < 8; ++j) { float v = xp[lane + 64 * j]; s += v * v; }
#pragma unroll
    for (int off = 32; off; off >>= 1) s += __shfl_down(s, off, 64);
    if (lane == 0) x2[row] = s;
}

__global__ __launch_bounds__(256) void colsq_k(const float* __restrict__ E,
                                               float* __restrict__ e2) {
    int k = blockIdx.x * 256 + threadIdx.x;
    float s = 0.f;
#pragma unroll 8
    for (int d = 0; d < DIMD; ++d) { float v = E[(size_t)d * NE + k]; s += v * v; }
    e2[k] = s;
}

// 128x128 tile, BK=8, 256 threads, 8x8 per thread (2x2 blocks of 4x4).
// Double-buffered LDS: ONE barrier per K-step; next tile's global loads
// issue right after the barrier and complete under the 8x64-FMA body.
__global__ __launch_bounds__(256) void dist_gemm(const float* __restrict__ X,
                                                 const float* __restrict__ E,
                                                 const float* __restrict__ x2v,
                                                 const float* __restrict__ e2v,
                                                 float* __restrict__ dist,
                                                 unsigned long long* __restrict__ packed) {
    __shared__ float As[2][8][132];
    __shared__ float Bs[2][8][132];
    __shared__ float stg[8][128];

    const int tid = threadIdx.x;
    const int tx = tid & 15;   // col group
    const int ty = tid >> 4;   // row group
    const int row0 = blockIdx.y * 128;
    const int col0 = blockIdx.x * 128;

    const int xr = tid >> 1, xc = (tid & 1) * 4;   // X tile: 128 rows x 8 cols
    const int er = tid >> 5, ec = (tid & 31) * 4;  // E tile: 8 rows x 128 cols
    const float* Xp = X + (size_t)(row0 + xr) * DIMD + xc;
    const float* Ep = E + (size_t)er * NE + col0 + ec;

    float acc[2][2][4][4];
#pragma unroll
    for (int a = 0; a < 2; ++a)
#pragma unroll
        for (int b = 0; b < 2; ++b)
#pragma unroll
            for (int i = 0; i < 4; ++i)
#pragma unroll
                for (int j = 0; j < 4; ++j) acc[a][b][i][j] = 0.f;

    // prologue: stage first K-tile into buffer 0
    {
        const float4 xv = *(const float4*)(Xp);
        const float4 ev = *(const float4*)(Ep);
        As[0][xc + 0][xr] = xv.x; As[0][xc + 1][xr] = xv.y;
        As[0][xc + 2][xr] = xv.z; As[0][xc + 3][xr] = xv.w;
        *(float4*)&Bs[0][er][ec] = ev;
    }

    int cur = 0;
    for (int d0 = 8; d0 < DIMD; d0 += 8) {
        __syncthreads();  // publish buf[cur]; prior reads of buf[cur^1] done
        // issue next tile's loads immediately (latency hides under FMA body)
        const float4 xv = *(const float4*)(Xp + d0);
        const float4 ev = *(const float4*)(Ep + (size_t)d0 * NE);
#pragma unroll
        for (int kk = 0; kk < 8; ++kk) {
            float a[2][4], b[2][4];
            *(float4*)&a[0][0] = *(const float4*)&As[cur][kk][ty * 4];
            *(float4*)&a[1][0] = *(const float4*)&As[cur][kk][64 + ty * 4];
            *(float4*)&b[0][0] = *(const float4*)&Bs[cur][kk][tx * 4];
            *(float4*)&b[1][0] = *(const float4*)&Bs[cur][kk][64 + tx * 4];
#pragma unroll
            for (int ri = 0; ri < 2; ++ri)
#pragma unroll
                for (int ci = 0; ci < 2; ++ci)
#pragma unroll
                    for (int i = 0; i < 4; ++i)
#pragma unroll
                        for (int j = 0; j < 4; ++j)
                            acc[ri][ci][i][j] = fmaf(a[ri][i], b[ci][j], acc[ri][ci][i][j]);
        }
        const int nxt = cur ^ 1;
        As[nxt][xc + 0][xr] = xv.x; As[nxt][xc + 1][xr] = xv.y;
        As[nxt][xc + 2][xr] = xv.z; As[nxt][xc + 3][xr] = xv.w;
        *(float4*)&Bs[nxt][er][ec] = ev;
        cur = nxt;
    }

    __syncthreads();
#pragma unroll
    for (int kk = 0; kk < 8; ++kk) {
        float a[2][4], b[2][4];
        *(float4*)&a[0][0] = *(const float4*)&As[cur][kk][ty * 4];
        *(float4*)&a[1][0] = *(const float4*)&As[cur][kk][64 + ty * 4];
        *(float4*)&b[0][0] = *(const float4*)&Bs[cur][kk][tx * 4];
        *(float4*)&b[1][0] = *(const float4*)&Bs[cur][kk][64 + tx * 4];
#pragma unroll
        for (int ri = 0; ri < 2; ++ri)
#pragma unroll
            for (int ci = 0; ci < 2; ++ci)
#pragma unroll
                for (int i = 0; i < 4; ++i)
#pragma unroll
                    for (int j = 0; j < 4; ++j)
                        acc[ri][ci][i][j] = fmaf(a[ri][i], b[ci][j], acc[ri][ci][i][j]);
    }

    // epilogue: dist = (x2 - 2*dot) + e2 ; fused per-row argmin
    float xs[2][4], es[2][4];
#pragma unroll
    for (int ri = 0; ri < 2; ++ri)
#pragma unroll
        for (int i = 0; i < 4; ++i) xs[ri][i] = x2v[row0 + ri * 64 + ty * 4 + i];
#pragma unroll
    for (int ci = 0; ci < 2; ++ci)
#pragma unroll
        for (int j = 0; j < 4; ++j) es[ci][j] = e2v[col0 + ci * 64 + tx * 4 + j];

    unsigned long long pk[2][4];
#pragma unroll
    for (int ri = 0; ri < 2; ++ri)
#pragma unroll
        for (int i = 0; i < 4; ++i) pk[ri][i] = ~0ULL;

#pragma unroll
    for (int ri = 0; ri < 2; ++ri)
#pragma unroll
        for (int ci = 0; ci < 2; ++ci)
#pragma unroll
            for (int i = 0; i < 4; ++i)
#pragma unroll
                for (int j = 0; j < 4; ++j) {
                    float dv = (xs[ri][i] - 2.0f * acc[ri][ci][i][j]) + es[ci][j];
                    acc[ri][ci][i][j] = dv;
                    unsigned ub = __float_as_uint(dv);
                    ub = ub ^ (unsigned)(((int)ub >> 31) | 0x80000000);
                    unsigned long long cand =
                        ((unsigned long long)ub << 32) |
                        (unsigned)(col0 + ci * 64 + tx * 4 + j);
                    if (cand < pk[ri][i]) pk[ri][i] = cand;
                }

#pragma unroll
    for (int ri = 0; ri < 2; ++ri)
#pragma unroll
        for (int i = 0; i < 4; ++i) {
            unsigned long long p = pk[ri][i];
#pragma unroll
            for (int off = 8; off; off >>= 1) {
                unsigned long long o = __shfl_down(p, off, 16);
                if (o < p) p = o;
            }
            if (tx == 0) atomicMin(&packed[row0 + ri * 64 + ty * 4 + i], p);
        }

    // staged coalesced dist stores (DIST region is only 4B-aligned -> scalar dwords)
    // nt stores: dist is 1.07 GB streaming, never re-read -> don't evict E/X from L2
#pragma unroll 1
    for (int c = 0; c < 16; ++c) {
        int ri = c >> 3;
        __syncthreads();
        if ((ty >> 1) == (c & 7)) {
            int r = (ty & 1) * 4;
#pragma unroll
            for (int i = 0; i < 4; ++i)
#pragma unroll
                for (int ci = 0; ci < 2; ++ci)
                    *(float4*)&stg[r + i][ci * 64 + tx * 4] = *(float4*)&acc[ri][ci][i][0];
        }
        __syncthreads();
#pragma unroll
        for (int jj = 0; jj < 4; ++jj) {
            int w = tid + 256 * jj;
            int rr = w >> 7, cc = w & 127;
            __builtin_nontemporal_store(((const float*)stg)[w],
                &dist[(size_t)(row0 + c * 8 + rr) * NE + col0 + cc]);
        }
    }
}

__global__ __launch_bounds__(256) void gather_k(const float* __restrict__ X,
                                                const float* __restrict__ E,
                                                const unsigned long long* __restrict__ packed,
                                                float* __restrict__ qst,
                                                float* __restrict__ indf,
                                                float* __restrict__ loss) {
    int wid = threadIdx.x >> 6, lane = threadIdx.x & 63;
    int row = blockIdx.x * 4 + wid;
    unsigned long long p = packed[row];
    int k = (int)(unsigned)(p & 0xFFFFFFFFULL);
    const float* xp = X + (size_t)row * DIMD;
    float* qp = qst + (size_t)row * DIMD;
    float ls = 0.f;
#pragma unroll
    for (int j = 0; j < 8; ++j) {
        int d = lane + 64 * j;
        float e = E[(size_t)d * NE + k];
        float x = xp[d];
        __builtin_nontemporal_store(x + (e - x), &qp[d]);  // straight-through numerics
        float df = x - e;
        ls += df * df;
    }
#pragma unroll
    for (int off = 32; off; off >>= 1) ls += __shfl_down(ls, off, 64);
    if (lane == 0) {
        atomicAdd(loss, ls * (1.0f / ((float)NTOK * (float)DIMD)));
        indf[row] = (float)k;
    }
}

extern "C" void kernel_launch(void* const* d_in, const int* in_sizes, int n_in,
                              void* d_out, int out_size, void* d_ws, size_t ws_size,
                              hipStream_t stream) {
    const float* X = (const float*)d_in[0];
    const float* E = (const float*)d_in[1];
    float* out = (float*)d_out;

    unsigned long long* packed = (unsigned long long*)d_ws;
    float* x2 = (float*)((char*)d_ws + 262144);
    float* e2 = (float*)((char*)d_ws + 393216);

    float* qst  = out + Q_OFF;
    float* indf = out + IND_OFF;
    float* loss = out + LOSS_OFF;
    float* dist = out + DIST_OFF;

    hipLaunchKernelGGL(init_k, dim3(NTOK / 256), dim3(256), 0, stream, packed, loss);
    hipLaunchKernelGGL(rowsq_k, dim3(NTOK / 4), dim3(256), 0, stream, X, x2);
    hipLaunchKernelGGL(colsq_k, dim3(NE / 256), dim3(256), 0, stream, E, e2);
    hipLaunchKernelGGL(dist_gemm, dim3(NE / 128, NTOK / 128), dim3(256), 0, stream,
                       X, E, x2, e2, dist, packed);
    hipLaunchKernelGGL(gather_k, dim3(NTOK / 4), dim3(256), 0, stream,
                       X, E, packed, qst, indf, loss);
}